// Round 1
// 391.749 us; speedup vs baseline: 1.0023x; 1.0023x over previous
//
#include <hip/hip_runtime.h>
#include <stdint.h>

#define B_ 32
#define S_ 8192
#define D_ 256
#define Q_ 256
#define U_ 128
#define NCHUNK 128   // S_/64 chunks per batch (M=64 rows per block)

typedef float floatx4 __attribute__((ext_vector_type(4)));
typedef float f32x4 __attribute__((ext_vector_type(4)));
typedef __bf16 bf16x8 __attribute__((ext_vector_type(8)));
typedef unsigned short ushortx4 __attribute__((ext_vector_type(4)));
typedef unsigned short ushortx8 __attribute__((ext_vector_type(8)));

static __device__ __forceinline__ unsigned short f2bf(float f) {
    unsigned int x = __builtin_bit_cast(unsigned int, f);
    x += 0x7FFFu + ((x >> 16) & 1u);   // RNE (inputs are finite/normal)
    return (unsigned short)(x >> 16);
}

static __device__ __forceinline__ float bf2f(unsigned short u) {
    unsigned int x = ((unsigned int)u) << 16;
    return __builtin_bit_cast(float, x);
}

static __device__ __forceinline__ float fast_tanh(float x) {
    x = fminf(15.f, fmaxf(-15.f, x));
    float e = __expf(2.f * x);
    return __fdividef(e - 1.f, e + 1.f);
}

// Kernel 1: proj_q[b][u] = sum_q query[b][q]*W2[q][u]; W1^T -> bf16 in ws,
// fragment-major layout: element (n,k) at (k>>5)*4096 + n*32 + (k&31).
// A wave's MFMA B-fragment load (16 lanes cc x 4 lanes qg x 16B) is then one
// contiguous, fully-coalesced 1 KiB region -> direct global->reg, no LDS.
__global__ __launch_bounds__(128) void prep_kernel(
        const float* __restrict__ query, const float* __restrict__ W1,
        const float* __restrict__ W2, float* __restrict__ pq,
        unsigned short* __restrict__ w1t) {
    int b = blockIdx.x;
    int t = threadIdx.x;  // 0..127
    __shared__ float qrow[Q_];
    qrow[t] = query[b * Q_ + t];
    qrow[t + 128] = query[b * Q_ + 128 + t];
    __syncthreads();
    float acc = 0.f;
#pragma unroll 8
    for (int q = 0; q < Q_; ++q) acc = fmaf(qrow[q], W2[q * U_ + t], acc);
    pq[b * U_ + t] = acc;
    int base = (b * 128 + t) * 8;     // 8 consecutive elements, same n
    int n = base >> 8, k0 = base & 255;
    ushortx8 u;
#pragma unroll
    for (int j = 0; j < 8; ++j) u[j] = f2bf(W1[(k0 + j) * U_ + n]);
    *reinterpret_cast<ushortx8*>(&w1t[(k0 >> 5) * 4096 + n * 32 + (k0 & 31)]) = u;
}

// Kernel 2 (fused): per (b, 64-row chunk):
//   A tile 64x256 bf16 in LDS (32 KiB, XOR swizzle), staged per 64-k slice,
//   ONE raw s_barrier per K-step (slices disjoint -> write(kt+1) overlaps
//   reads of kt); loads stay in flight across barriers (counted waits).
//   B fragments come straight from L2-hot w1t into a register double-buffer.
//   37 KiB LDS + <=128 VGPR -> 4 blocks/CU. Scores -> ws; local softmax
//   stats; partial context from LDS bf16 (single HBM pass over values).
__global__ __launch_bounds__(256, 4) void fused_kernel(
        const float* __restrict__ values, const unsigned short* __restrict__ w1t,
        const float* __restrict__ pq, const float* __restrict__ V,
        float* __restrict__ scores, float* __restrict__ mbuf,
        float* __restrict__ lbuf, float* __restrict__ cpart) {
    __shared__ __align__(16) char smem[32768 + 4096 + 512 + 256];
    unsigned short* As = (unsigned short*)smem;            // 64 x 256 ushorts, swizzled
    floatx4* cbuf = (floatx4*)(smem + 32768);              // 256 f4
    float* part = (float*)(smem + 32768 + 4096);           // 128 f
    float* parr = (float*)(smem + 32768 + 4096 + 512);     // 64 f

    int b = blockIdx.y;
    int cid = blockIdx.x;
    int s0 = cid * 64;
    int tid = threadIdx.x;
    int lane = tid & 63;
    int wave = tid >> 6;
    int wr = wave >> 1, wc = wave & 1;
    int cc = lane & 15, qg = lane >> 4;
    int cc7 = cc & 7;

    const float* vb = values + ((size_t)b * S_ + s0) * D_;

    f32x4 acc[2][4];
#pragma unroll
    for (int mt = 0; mt < 2; ++mt)
#pragma unroll
        for (int nt = 0; nt < 4; ++nt) acc[mt][nt] = (f32x4){0.f, 0.f, 0.f, 0.f};

    // A staging: per kt slice, thread handles 2 (row, 8k-chunk) pairs ->
    // 4 float4 loads, 2 ds_write_b128 (fewer LDS ops than b64 variant).
    int arow = tid >> 3;   // 0..31 (+32 for j=1)
    int ac8 = tid & 7;     // 8-float chunk within 64-k slice
    floatx4 areg[4];
    auto load_a = [&](int kt) {
#pragma unroll
        for (int j = 0; j < 2; ++j) {
            const float* src = vb + (size_t)(arow + j * 32) * D_ + kt * 64 + ac8 * 8;
            areg[j * 2]     = *reinterpret_cast<const floatx4*>(src);
            areg[j * 2 + 1] = *reinterpret_cast<const floatx4*>(src + 4);
        }
    };
    auto write_a = [&](int kt) {
#pragma unroll
        for (int j = 0; j < 2; ++j) {
            int row = arow + j * 32;
            ushortx8 u;
#pragma unroll
            for (int e = 0; e < 4; ++e) {
                u[e]     = f2bf(areg[j * 2][e]);
                u[e + 4] = f2bf(areg[j * 2 + 1][e]);
            }
            int chunk = kt * 8 + ac8;                     // 16B chunk index [0,32)
            *reinterpret_cast<ushortx8*>(
                &As[row * 256 + ((chunk ^ (row & 7)) << 3)]) = u;
        }
    };

    // B fragment register double-buffer, direct from global (L2/L1-hot).
    bf16x8 bb[2][4];
    const unsigned short* wbase = w1t + (wc * 64 + cc) * 32 + qg * 8;
    auto load_b = [&](int ksg, int buf) {
#pragma unroll
        for (int nt = 0; nt < 4; ++nt)
            bb[buf][nt] = *reinterpret_cast<const bf16x8*>(wbase + ksg * 4096 + nt * 512);
    };

    load_a(0);
    write_a(0);                       // waits on A(0) loads only
    load_a(1);                        // in flight across the barrier
    load_b(0, 0);                     // in flight across the barrier
    asm volatile("s_waitcnt lgkmcnt(0)" ::: "memory");   // A(0) ds_writes visible
    __builtin_amdgcn_s_barrier();

#pragma unroll
    for (int kt = 0; kt < 4; ++kt) {
#pragma unroll
        for (int s = 0; s < 2; ++s) {
            int ksg = kt * 2 + s;
            if (ksg < 7) load_b(ksg + 1, (ksg + 1) & 1);   // prefetch next ksg
            bf16x8 af[2];
#pragma unroll
            for (int mt = 0; mt < 2; ++mt) {
                int r = wr * 32 + mt * 16 + cc;
                af[mt] = *reinterpret_cast<const bf16x8*>(
                    &As[r * 256 + (((ksg * 4 + qg) ^ cc7) << 3)]);
            }
            __builtin_amdgcn_s_setprio(1);
#pragma unroll
            for (int mt = 0; mt < 2; ++mt)
#pragma unroll
                for (int nt = 0; nt < 4; ++nt)
                    acc[mt][nt] = __builtin_amdgcn_mfma_f32_16x16x32_bf16(
                        af[mt], bb[ksg & 1][nt], acc[mt][nt], 0, 0, 0);
            __builtin_amdgcn_s_setprio(0);
        }
        if (kt < 3) {
            write_a(kt + 1);          // slice kt+1 disjoint from kt being read
            if (kt < 2) load_a(kt + 2);
            asm volatile("s_waitcnt lgkmcnt(0)" ::: "memory");
            __builtin_amdgcn_s_barrier();   // slice kt+1 now visible
        }
    }

    // tanh + dot-V epilogue -> per-row score partials
    float Vu[4], pqu[4];
#pragma unroll
    for (int nt = 0; nt < 4; ++nt) {
        int u = wc * 64 + nt * 16 + cc;
        Vu[nt] = V[u];
        pqu[nt] = pq[b * U_ + u];
    }
#pragma unroll
    for (int mt = 0; mt < 2; ++mt) {
#pragma unroll
        for (int r = 0; r < 4; ++r) {
            float s = 0.f;
#pragma unroll
            for (int nt = 0; nt < 4; ++nt)
                s += Vu[nt] * fast_tanh(acc[mt][nt][r] + pqu[nt]);
            s += __shfl_xor(s, 1);
            s += __shfl_xor(s, 2);
            s += __shfl_xor(s, 4);
            s += __shfl_xor(s, 8);
            if (cc == 0) part[wc * 64 + wr * 32 + mt * 16 + qg * 4 + r] = s;
        }
    }
    __syncthreads();
    // single tid<64 section: combine halves, write scores, butterfly max+sum
    // (butterfly leaves the result in every lane -> no LDS broadcast round-trip)
    if (tid < 64) {
        float sc = part[tid] + part[64 + tid];
        scores[(size_t)b * S_ + s0 + tid] = sc;
        float m = sc;
#pragma unroll
        for (int off = 32; off >= 1; off >>= 1) m = fmaxf(m, __shfl_xor(m, off));
        float p = __expf(sc - m);
        float l = p;
#pragma unroll
        for (int off = 32; off >= 1; off >>= 1) l += __shfl_xor(l, off);
        parr[tid] = p;
        if (tid == 0) { mbuf[b * NCHUNK + cid] = m; lbuf[b * NCHUNK + cid] = l; }
    }
    __syncthreads();

    // partial context from LDS bf16 tile (wave-uniform row; conflict-free).
    int g = tid & 63, sub = tid >> 6;
    floatx4 acc4 = {0.f, 0.f, 0.f, 0.f};
#pragma unroll 4
    for (int i = 0; i < 16; ++i) {
        int r = i * 4 + sub;
        float w = parr[r];
        int addr = r * 256 + (((g >> 1) ^ (r & 7)) << 3) + (g & 1) * 4;
        ushortx4 u = *reinterpret_cast<const ushortx4*>(&As[addr]);
        acc4[0] = fmaf(bf2f(u[0]), w, acc4[0]);
        acc4[1] = fmaf(bf2f(u[1]), w, acc4[1]);
        acc4[2] = fmaf(bf2f(u[2]), w, acc4[2]);
        acc4[3] = fmaf(bf2f(u[3]), w, acc4[3]);
    }
    cbuf[tid] = acc4;
    __syncthreads();
    if (tid < 64) {
        floatx4 r4 = cbuf[tid] + cbuf[tid + 64] + cbuf[tid + 128] + cbuf[tid + 192];
        *reinterpret_cast<floatx4*>(cpart + ((size_t)b * NCHUNK + cid) * D_ + g * 4) = r4;
    }
}

// Kernel 3: grid (B_, 9). y<8: write 1024 weights; y==8: combined context.
__global__ __launch_bounds__(256) void finalize_kernel(
        const float* __restrict__ scores, const float* __restrict__ mbuf,
        const float* __restrict__ lbuf, const float* __restrict__ cpart,
        float* __restrict__ out) {
    int b = blockIdx.x;
    int part_id = blockIdx.y;
    int tid = threadIdx.x;
    __shared__ float wred[4];
    __shared__ float alpha[NCHUNK];
    if (tid < NCHUNK) {
        float m = mbuf[b * NCHUNK + tid];
#pragma unroll
        for (int off = 32; off >= 1; off >>= 1) m = fmaxf(m, __shfl_xor(m, off));
        if ((tid & 63) == 0) wred[tid >> 6] = m;
    }
    __syncthreads();
    float M = fmaxf(wred[0], wred[1]);
    if (tid < NCHUNK) {
        float z = lbuf[b * NCHUNK + tid] * __expf(mbuf[b * NCHUNK + tid] - M);
#pragma unroll
        for (int off = 32; off >= 1; off >>= 1) z += __shfl_xor(z, off);
        if ((tid & 63) == 0) wred[2 + (tid >> 6)] = z;
    }
    __syncthreads();
    float invZ = 1.f / (wred[2] + wred[3]);

    if (part_id < 8) {
        size_t off = (size_t)b * S_ + part_id * 1024;
        floatx4 v = *reinterpret_cast<const floatx4*>(scores + off + tid * 4);
        floatx4 w;
#pragma unroll
        for (int j = 0; j < 4; ++j) w[j] = __expf(v[j] - M) * invZ;
        *reinterpret_cast<floatx4*>(out + B_ * D_ + off + tid * 4) = w;
    } else {
        if (tid < NCHUNK) alpha[tid] = __expf(mbuf[b * NCHUNK + tid] - M) * invZ;
        __syncthreads();
        float acc = 0.f;
#pragma unroll 8
        for (int c = 0; c < NCHUNK; ++c)
            acc = fmaf(alpha[c], cpart[((size_t)b * NCHUNK + c) * D_ + tid], acc);
        out[b * D_ + tid] = acc;
    }
}

extern "C" void kernel_launch(void* const* d_in, const int* in_sizes, int n_in,
                              void* d_out, int out_size, void* d_ws, size_t ws_size,
                              hipStream_t stream) {
    const float* query  = (const float*)d_in[0];
    const float* values = (const float*)d_in[1];
    const float* W1     = (const float*)d_in[2];
    const float* W2     = (const float*)d_in[3];
    const float* V      = (const float*)d_in[4];
    float* out = (float*)d_out;

    char* ws = (char*)d_ws;
    unsigned short* w1t = (unsigned short*)ws;               ws += 65536;           // 64 KiB
    float* pq     = (float*)ws;                              ws += 16384;           // 16 KiB
    float* scores = (float*)ws;                              ws += B_ * S_ * 4;     // 1 MiB
    float* mbuf   = (float*)ws;                              ws += B_ * NCHUNK * 4; // 16 KiB
    float* lbuf   = (float*)ws;                              ws += B_ * NCHUNK * 4; // 16 KiB
    float* cpart  = (float*)ws;                                                    // 4 MiB

    prep_kernel<<<dim3(32), dim3(128), 0, stream>>>(query, W1, W2, pq, w1t);
    fused_kernel<<<dim3(NCHUNK, B_), dim3(256), 0, stream>>>(values, w1t, pq, V,
                                                             scores, mbuf, lbuf, cpart);
    finalize_kernel<<<dim3(B_, 9), dim3(256), 0, stream>>>(scores, mbuf, lbuf, cpart, out);
}